// Round 3
// baseline (316.765 us; speedup 1.0000x reference)
//
#include <hip/hip_runtime.h>
#include <hip/hip_cooperative_groups.h>

namespace cg = cooperative_groups;

#define IMG 512
#define HW (IMG * IMG)      // 262144
#define NB 257              // bins
#define BATCH 16
#define RG 64               // row-groups per image (8 rows each)

// plane(h,w): h==0||w==0 -> 256; else 255 - min(m_h, d_w),
// m_h = min(h-1,511-h), d_w = min(w-1,511-w).
// Row h>=1: w=0 -> 256; d_w < m_h -> ramp bin 255-d_w; d_w >= m_h -> constant 255-m_h.

__global__ __launch_bounds__(256, 4) void fused_kernel(
    const float* __restrict__ x,       // [16,3,512,512]
    const float* __restrict__ mask_n,  // [257]
    float* __restrict__ out,           // [16,257]
    float* __restrict__ partial,       // [16*64,257] ws
    float* __restrict__ profile)       // [16,257]    ws
{
    const int gx   = blockIdx.x;        // row-group
    const int b    = blockIdx.y;        // image
    const int wid  = threadIdx.x >> 6;
    const int lane = threadIdx.x & 63;

    __shared__ float bins[NB];
    for (int i = threadIdx.x; i < NB; i += 256) bins[i] = 0.f;
    __syncthreads();

    const float* xbase = x + (size_t)b * 3 * HW;
    const int h0 = gx << 3;

    // ---- phase 1: 8 rows per block, 2 rows per wave, LDS histogram ----
#pragma unroll
    for (int rr = 0; rr < 2; ++rr) {
        const int h = h0 + (wid << 1) + rr;
        const float* xr  = xbase + (size_t)h * IMG;
        const float* xg  = xr + HW;
        const float* xbl = xg + HW;
        const int m = min(h - 1, 511 - h);   // meaningful for h>=1
        float mid = 0.f;
#pragma unroll
        for (int j = 0; j < 2; ++j) {
            const int w0 = (((j << 6) + lane) << 2);   // 4 consecutive pixels
            const float4 r  = *reinterpret_cast<const float4*>(xr  + w0);
            const float4 g  = *reinterpret_cast<const float4*>(xg  + w0);
            const float4 bv = *reinterpret_cast<const float4*>(xbl + w0);
            float mg[4];
            mg[0] = 20.f * (0.299f * r.x + 0.587f * g.x + 0.114f * bv.x);
            mg[1] = 20.f * (0.299f * r.y + 0.587f * g.y + 0.114f * bv.y);
            mg[2] = 20.f * (0.299f * r.z + 0.587f * g.z + 0.114f * bv.z);
            mg[3] = 20.f * (0.299f * r.w + 0.587f * g.w + 0.114f * bv.w);

            if (h == 0) {
                mid += mg[0] + mg[1] + mg[2] + mg[3];   // whole row -> bin 256
            } else {
#pragma unroll
                for (int t = 0; t < 4; ++t) {
                    const int w = w0 + t;
                    if (w == 0) {
                        atomicAdd(&bins[256], mg[t]);   // lane 0 only
                    } else {
                        const int d = min(w - 1, 511 - w);
                        if (d >= m) mid += mg[t];                    // constant middle bin
                        else        atomicAdd(&bins[255 - d], mg[t]); // distinct ramp addrs
                    }
                }
            }
        }
        // per-row butterfly: middle-run sum -> one LDS atomic per wave-row
#pragma unroll
        for (int off = 32; off > 0; off >>= 1) mid += __shfl_down(mid, off, 64);
        if (lane == 0) atomicAdd(&bins[(h == 0) ? 256 : (255 - m)], mid);
    }
    __syncthreads();

    // plain coalesced partial store — no global atomics
    float* pp = partial + ((size_t)b * RG + gx) * NB;
    for (int i = threadIdx.x; i < NB; i += 256) pp[i] = bins[i];
    __threadfence();

    cg::this_grid().sync();

    // ---- phase 2: 16 blocks reduce 64 partials each ----
    const int gid = b * RG + gx;   // linear block id (b=blockIdx.y major)
    if (gid < BATCH) {
        const float* p0 = partial + (size_t)gid * RG * NB;
        for (int l = threadIdx.x; l < NB; l += 256) {
            float s = 0.f;
#pragma unroll 8
            for (int g = 0; g < RG; ++g) s += p0[(size_t)g * NB + l];
            profile[gid * NB + l] = s / mask_n[l];
        }
        __threadfence();
    }

    cg::this_grid().sync();

    // ---- phase 3: block 0 min/max + normalize ----
    if (gid == 0) {
        __shared__ float smin[256];
        __shared__ float smax[256];
        float lmin = 3.402823466e+38f, lmax = -3.402823466e+38f;
        for (int i = threadIdx.x; i < BATCH * NB; i += 256) {
            const float v = profile[i];
            lmin = fminf(lmin, v);
            lmax = fmaxf(lmax, v);
        }
        smin[threadIdx.x] = lmin;
        smax[threadIdx.x] = lmax;
        __syncthreads();
        for (int s = 128; s > 0; s >>= 1) {
            if (threadIdx.x < s) {
                smin[threadIdx.x] = fminf(smin[threadIdx.x], smin[threadIdx.x + s]);
                smax[threadIdx.x] = fmaxf(smax[threadIdx.x], smax[threadIdx.x + s]);
            }
            __syncthreads();
        }
        const float pmin = smin[0];
        const float inv = 1.f / (smax[0] - pmin);
        for (int i = threadIdx.x; i < BATCH * NB; i += 256)
            out[i] = (profile[i] - pmin) * inv;
    }
}

extern "C" void kernel_launch(void* const* d_in, const int* in_sizes, int n_in,
                              void* d_out, int out_size, void* d_ws, size_t ws_size,
                              hipStream_t stream) {
    const float* x      = (const float*)d_in[0];   // [16,3,512,512] f32
    const float* mask_n = (const float*)d_in[2];   // [257] f32 (mask d_in[1] unused)
    float* out     = (float*)d_out;
    float* partial = (float*)d_ws;                          // 16*64*257 floats
    float* profile = partial + (size_t)BATCH * RG * NB;     // 16*257 floats

    void* args[] = {(void*)&x, (void*)&mask_n, (void*)&out,
                    (void*)&partial, (void*)&profile};
    hipLaunchCooperativeKernel((const void*)fused_kernel,
                               dim3(RG, BATCH), dim3(256),
                               args, 0, stream);
}

// Round 4
// 38.753 us; speedup vs baseline: 8.1740x; 8.1740x over previous
//
#include <hip/hip_runtime.h>

#define IMG 512
#define HW (IMG * IMG)      // 262144
#define NB 257              // bins
#define BATCH 16
#define RG 32               // row-groups per image (16 rows each)

// plane(h,w): h==0||w==0 -> 256; else 255 - min(m_h, d_w),
// m_h = min(h-1,511-h), d_w = min(w-1,511-w).
// Row h>=1: w=0 -> bin 256; d_w < m_h -> ramp bin 255-d_w (distinct addrs
// within the row side); d_w >= m_h -> constant bin 255-m_h (wave-reduced).

__global__ __launch_bounds__(256) void hist_kernel(const float* __restrict__ x,
                                                   float* __restrict__ partial) {
    const int gx   = blockIdx.x;        // row-group 0..31
    const int b    = blockIdx.y;        // image 0..15
    const int wid  = threadIdx.x >> 6;
    const int lane = threadIdx.x & 63;

    __shared__ float bins[NB];
    for (int i = threadIdx.x; i < NB; i += 256) bins[i] = 0.f;
    __syncthreads();

    const float* xbase = x + (size_t)b * 3 * HW;
    const int h0 = (gx << 4) + (wid << 2);   // 4 rows per wave

#pragma unroll
    for (int rr = 0; rr < 4; ++rr) {
        const int h = h0 + rr;
        const float* xr  = xbase + (size_t)h * IMG;
        const float* xg  = xr + HW;
        const float* xbl = xg + HW;
        const int m = min(h - 1, 511 - h);   // meaningful for h>=1
        float mid = 0.f;
#pragma unroll
        for (int j = 0; j < 2; ++j) {
            const int w0 = (((j << 6) + lane) << 2);   // 4 consecutive pixels
            const float4 r  = *reinterpret_cast<const float4*>(xr  + w0);
            const float4 g  = *reinterpret_cast<const float4*>(xg  + w0);
            const float4 bv = *reinterpret_cast<const float4*>(xbl + w0);
            float mg[4];
            mg[0] = 20.f * (0.299f * r.x + 0.587f * g.x + 0.114f * bv.x);
            mg[1] = 20.f * (0.299f * r.y + 0.587f * g.y + 0.114f * bv.y);
            mg[2] = 20.f * (0.299f * r.z + 0.587f * g.z + 0.114f * bv.z);
            mg[3] = 20.f * (0.299f * r.w + 0.587f * g.w + 0.114f * bv.w);

            if (h == 0) {
                mid += mg[0] + mg[1] + mg[2] + mg[3];   // whole row -> bin 256
            } else {
#pragma unroll
                for (int t = 0; t < 4; ++t) {
                    const int w = w0 + t;
                    if (w == 0) {
                        atomicAdd(&bins[256], mg[t]);   // lane 0 only
                    } else {
                        const int d = min(w - 1, 511 - w);
                        if (d >= m) mid += mg[t];                     // constant middle bin
                        else        atomicAdd(&bins[255 - d], mg[t]); // distinct ramp addrs
                    }
                }
            }
        }
        // per-row wave butterfly: middle-run sum -> one LDS atomic per row
#pragma unroll
        for (int off = 32; off > 0; off >>= 1) mid += __shfl_down(mid, off, 64);
        if (lane == 0) atomicAdd(&bins[(h == 0) ? 256 : (255 - m)], mid);
    }
    __syncthreads();

    // plain coalesced partial store — zero global atomics
    float* pp = partial + ((size_t)b * RG + gx) * NB;
    for (int i = threadIdx.x; i < NB; i += 256) pp[i] = bins[i];
}

__global__ __launch_bounds__(1024) void finalize_kernel(const float* __restrict__ partial,
                                                        const float* __restrict__ mask_n,
                                                        float* __restrict__ out) {
    __shared__ float prof_s[BATCH * NB];   // 4112 floats, 16.4 KB
    __shared__ float red_min[16];
    __shared__ float red_max[16];

    const int lane = threadIdx.x & 63;
    const int wv   = threadIdx.x >> 6;

    float lmin = 3.402823466e+38f, lmax = -3.402823466e+38f;
    for (int i = threadIdx.x; i < BATCH * NB; i += 1024) {
        const int bb = i / NB;
        const int l  = i - bb * NB;
        const float* p = partial + (size_t)bb * RG * NB + l;
        float s = 0.f;
#pragma unroll
        for (int g = 0; g < RG; ++g) s += p[(size_t)g * NB];
        s /= mask_n[l];
        prof_s[i] = s;
        lmin = fminf(lmin, s);
        lmax = fmaxf(lmax, s);
    }
#pragma unroll
    for (int off = 32; off > 0; off >>= 1) {
        lmin = fminf(lmin, __shfl_xor(lmin, off, 64));
        lmax = fmaxf(lmax, __shfl_xor(lmax, off, 64));
    }
    if (lane == 0) { red_min[wv] = lmin; red_max[wv] = lmax; }
    __syncthreads();

    float pmin = red_min[0], pmax = red_max[0];
#pragma unroll
    for (int k = 1; k < 16; ++k) {
        pmin = fminf(pmin, red_min[k]);
        pmax = fmaxf(pmax, red_max[k]);
    }
    const float inv = 1.f / (pmax - pmin);
    for (int i = threadIdx.x; i < BATCH * NB; i += 1024)
        out[i] = (prof_s[i] - pmin) * inv;
}

extern "C" void kernel_launch(void* const* d_in, const int* in_sizes, int n_in,
                              void* d_out, int out_size, void* d_ws, size_t ws_size,
                              hipStream_t stream) {
    const float* x      = (const float*)d_in[0];   // [16,3,512,512] f32
    const float* mask_n = (const float*)d_in[2];   // [257] f32 (mask d_in[1] unused)
    float* out     = (float*)d_out;                // [16,257] f32
    float* partial = (float*)d_ws;                 // [16*32,257] f32

    hist_kernel<<<dim3(RG, BATCH), 256, 0, stream>>>(x, partial);
    finalize_kernel<<<1, 1024, 0, stream>>>(partial, mask_n, out);
}